// Round 11
// baseline (21358.702 us; speedup 1.0000x reference)
//
#include <hip/hip_runtime.h>

typedef unsigned short ushort_t;
typedef __attribute__((ext_vector_type(4))) float f4;
typedef __attribute__((ext_vector_type(4))) int   i4;

__device__ __forceinline__ float b2f(ushort_t u){
  union { unsigned int i; float f; } v; v.i = ((unsigned int)u) << 16; return v.f;
}
__device__ __forceinline__ ushort_t f2b(float f){
  union { float f; unsigned int i; } v; v.f = f;
  unsigned int u = v.i;
  return (ushort_t)((u + 0x7fffu + ((u >> 16) & 1u)) >> 16);
}
__device__ __forceinline__ float sigm(float x){ return 1.f/(1.f + __expf(-x)); }

// ---------------- fp32 -> bf16 convert with optional col-slice and zero padding ----------------
__global__ void cvt_pad(const float* __restrict__ src, ushort_t* __restrict__ dst,
                        int Rsrc, int Csrc, int col0, int Ccopy, int Cdst, long total){
  long i = (long)blockIdx.x*256 + threadIdx.x;
  if (i >= total) return;
  int r = (int)(i / Cdst), c = (int)(i % Cdst);
  float v = 0.f;
  if (r < Rsrc && c < Ccopy) v = src[(long)r*Csrc + col0 + c];
  dst[i] = f2b(v);
}

// ---------------- decoder weight fold ----------------
__global__ void fold_w(const float* __restrict__ Wih, const float* __restrict__ Whh,
                       const float* __restrict__ ctxW, ushort_t* __restrict__ out, int poff){
  int p = blockIdx.x*256 + threadIdx.x;     // 0..1023
  int q = blockIdx.y;                       // 0..2047
  if (p >= 1024) return;
  float s = 0.f;
  #pragma unroll 8
  for (int e=0;e<64;e++) s += Wih[q*256 + 192 + e] * ctxW[e*1024 + p];
  if (p >= poff && p < poff + 512) s += Whh[q*512 + (p - poff)];
  out[(long)q*1024 + p] = f2b(s);
}

__global__ void fold_b(const float* __restrict__ b, const float* __restrict__ Wih,
                       const float* __restrict__ ctxb, float* __restrict__ out){
  int q = blockIdx.x*256 + threadIdx.x;
  if (q >= 2048) return;
  float s = b[q];
  #pragma unroll 8
  for (int e=0;e<64;e++) s += ctxb[e]*Wih[q*256 + 192 + e];
  out[q] = s;
}

// ---------------- z = mu + exp(0.5*lv)*noise ; reshape [K,S,N,E] -> [S*N, K*E] bf16 ----------------
__global__ void z_make(const float* __restrict__ mu, const float* __restrict__ lv,
                       const float* __restrict__ noise, ushort_t* __restrict__ zb){
  long i = (long)blockIdx.x*256 + threadIdx.x;
  if (i >= 3L*800*32*64) return;
  int e = (int)(i & 63); int n = (int)((i>>6) & 31);
  long r = i >> 11; int s = (int)(r % 800); int k = (int)(r / 800);
  float z = mu[i] + __expf(0.5f*lv[i]) * noise[i];
  zb[((long)(s*32 + n))*192 + k*64 + e] = f2b(z);
}

__global__ void dec_init(const float* __restrict__ h0, const float* __restrict__ c0,
                         ushort_t* __restrict__ prev, float* __restrict__ cDF, float* __restrict__ cDB){
  int i = blockIdx.x*256 + threadIdx.x;
  if (i < 32*1024) prev[i] = f2b(h0[i & 1023]);
  if (i < 32*512){ cDF[i] = c0[i & 511]; cDB[i] = c0[512 + (i & 511)]; }
}

__global__ void fill1(float* __restrict__ p, long n){
  long i = (long)blockIdx.x*256 + threadIdx.x;
  if (i < n) p[i] = 1.f;
}

// ---------------- bf16 MFMA GEMM: C[m][n] = sum_k A[m][k]*B[n][k] + bias[n] ----------------
#define GLD 40
__global__ __launch_bounds__(256) void gemm_bt(
    const ushort_t* __restrict__ A, int lda,
    const ushort_t* __restrict__ B, int ldb,
    const float* __restrict__ bias, int K, int Nreal, int mode, int ldc,
    float* __restrict__ outF, ushort_t* __restrict__ outB)
{
  __shared__ ushort_t Al[128*GLD];
  __shared__ ushort_t Bl[128*GLD];
  int tid = threadIdx.x;
  int m0 = blockIdx.y * 128;
  int n0 = blockIdx.x * 128;
  int l = tid & 63, w = tid >> 6;
  int wm = w & 1, wn = w >> 1;
  int srow = tid >> 2;
  int scg  = tid & 3;

  f4 acc[4][4];
  #pragma unroll
  for (int i=0;i<4;i++)
    #pragma unroll
    for (int j=0;j<4;j++) acc[i][j] = (f4){0.f,0.f,0.f,0.f};

  i4 pa0, pa1, pb0, pb1;
  {
    long ab = (long)(m0 + srow)*lda + scg*8;
    pa0 = *(const i4*)&A[ab];
    pa1 = *(const i4*)&A[ab + 64L*lda];
    long bb = (long)(n0 + srow)*ldb + scg*8;
    pb0 = *(const i4*)&B[bb];
    pb1 = *(const i4*)&B[bb + 64L*ldb];
  }
  for (int k0 = 0; k0 < K; k0 += 32){
    __syncthreads();
    *(i4*)&Al[srow*GLD + scg*8]      = pa0;
    *(i4*)&Al[(srow+64)*GLD + scg*8] = pa1;
    *(i4*)&Bl[srow*GLD + scg*8]      = pb0;
    *(i4*)&Bl[(srow+64)*GLD + scg*8] = pb1;
    __syncthreads();
    if (k0 + 32 < K){
      long ab = (long)(m0 + srow)*lda + k0 + 32 + scg*8;
      pa0 = *(const i4*)&A[ab];
      pa1 = *(const i4*)&A[ab + 64L*lda];
      long bb = (long)(n0 + srow)*ldb + k0 + 32 + scg*8;
      pb0 = *(const i4*)&B[bb];
      pb1 = *(const i4*)&B[bb + 64L*ldb];
    }
    int kg = (l>>4)*8;
    i4 av[4], bv[4];
    #pragma unroll
    for (int r=0;r<4;r++)
      av[r] = *(const i4*)&Al[(wm*64 + r*16 + (l&15))*GLD + kg];
    #pragma unroll
    for (int r=0;r<4;r++)
      bv[r] = *(const i4*)&Bl[(wn*64 + r*16 + (l&15))*GLD + kg];
    #pragma unroll
    for (int i=0;i<4;i++)
      #pragma unroll
      for (int j=0;j<4;j++)
        asm volatile("v_mfma_f32_16x16x32_bf16 %0, %1, %2, %0"
                     : "+v"(acc[i][j]) : "v"(av[i]), "v"(bv[j]));
  }
  asm volatile("s_nop 7\n\ts_nop 7\n\ts_nop 7");
  int row_l = (l>>4)*4, col_l = l&15;
  #pragma unroll
  for (int i=0;i<4;i++){
    #pragma unroll
    for (int j=0;j<4;j++){
      int n = n0 + wn*64 + j*16 + col_l;
      if (n >= Nreal) continue;
      float bb = bias[n];
      #pragma unroll
      for (int r=0;r<4;r++){
        int m = m0 + wm*64 + i*16 + row_l + r;
        float v = acc[i][j][r] + bb;
        if (mode == 0){
          outF[(long)m*ldc + n] = v;
        } else if (mode == 1){
          outB[(long)m*ldc + n] = f2b(v);
        } else if (mode == 2){
          outB[(long)m*ldc + n] = f2b(tanhf(v));
        } else {
          outF[(long)(n>>6)*1638400 + (long)m*64 + (n&63)] = v;
        }
      }
    }
  }
}

// ---------------- persistent LSTM chunk v3: 64 fat blocks, LDS-staged A ----------------
// 64 blocks x 1024 thr: dir = bx>>5 (32 blocks/dir), 16 units u0=(bx&31)*16, all 4 gates.
// Wave w: gate g=w>>2, K-half ks=(w>>1)&1, batch-row-half rh=w&1. A staged once per block
// into LDS (XOR-swizzled 16B chunks); h exchange via L3 (sc1 stores / sc0 sc1 loads).
// Barrier: per-direction monotonic counters (32 arrivals each); decoder waits on both.
template<int KA>
__global__ __launch_bounds__(1024) void lstm_chunk(
    int nsteps, unsigned base,
    const ushort_t* __restrict__ initAf, const ushort_t* __restrict__ initAb,
    ushort_t* __restrict__ outF, ushort_t* __restrict__ outB,
    long oStrF, long oStrB, long aOffF, long aOffB,
    const ushort_t* __restrict__ preFb, const ushort_t* __restrict__ preBb,
    long pStrF, long pStrB,
    const ushort_t* __restrict__ Wf, const ushort_t* __restrict__ Wb,
    float* __restrict__ cF, float* __restrict__ cB,
    unsigned* barF, unsigned* barB, int joint)
{
  constexpr int H = KA/512;                 // 1 (enc) or 2 (dec) A-halves of 32KB
  __shared__ ushort_t Als[32*512];          // 32KB staged A half
  __shared__ float gl[2][4][32][16];        // 16KB partials [ks][gate][n][unit]
  int tid = threadIdx.x;
  int dir = blockIdx.x >> 5;
  int u0  = (blockIdx.x & 31) << 4;
  const ushort_t* W = dir ? Wb : Wf;
  float* c          = dir ? cB : cF;
  unsigned* barOwn  = dir ? barB : barF;
  unsigned* barOth  = dir ? barF : barB;

  int l = tid & 63, w = tid >> 6;
  int g  = w >> 2;            // gate
  int ks = (w >> 1) & 1;      // K half-slice within A-half
  int rh = w & 1;             // batch row half
  int col = l & 15;
  int qr  = l >> 4;
  int arow = col + rh*16;
  const ushort_t* Wr = &W[(long)(g*512 + u0 + col)*KA];

  int cn = tid >> 4, cu = tid & 15;
  float creg = 0.f;
  if (tid < 512) creg = c[cn*512 + u0 + cu];

  int lr0 = tid >> 6, lc0 = tid & 63;       // loader: row 0..15 / chunk
  int lr1 = lr0 + 16;                        // rows 16..31

  for (int js = 0; js < nsteps; ++js){
    const ushort_t* A = (js == 0)
        ? (dir ? initAb : initAf)
        : (const ushort_t*)(dir ? outB + (js-1)*oStrB + aOffB
                                : outF + (js-1)*oStrF + aOffF);
    const ushort_t* pre = dir ? preBb + js*pStrB : preFb + js*pStrF;
    ushort_t* out = dir ? outB + js*oStrB : outF + js*oStrF;

    f4 acc = (f4){0.f,0.f,0.f,0.f};
    #pragma unroll
    for (int half = 0; half < H; ++half){
      i4 v0, v1;
      {
        const ushort_t* g0 = A + lr0*1024 + half*512 + lc0*8;
        const ushort_t* g1 = A + lr1*1024 + half*512 + lc0*8;
        asm volatile("global_load_dwordx4 %0, %1, off sc0 sc1" : "=v"(v0) : "v"(g0));
        asm volatile("global_load_dwordx4 %0, %1, off sc0 sc1" : "=v"(v1) : "v"(g1));
      }
      asm volatile("s_waitcnt vmcnt(0)" ::: "memory");
      __syncthreads();                        // prior Als readers done
      *(i4*)&Als[lr0*512 + ((lc0 ^ (lr0 & 7))*8)] = v0;
      *(i4*)&Als[lr1*512 + ((lc0 ^ (lr1 & 7))*8)] = v1;
      __syncthreads();                        // staged
      #pragma unroll
      for (int t = 0; t < 8; ++t){
        int ch = ks*32 + qr + t*4;            // 16B chunk within half
        i4 a = *(const i4*)&Als[arow*512 + ((ch ^ (arow & 7))*8)];
        i4 b = *(const i4*)&Wr[half*512 + ks*256 + qr*8 + t*32];
        asm volatile("v_mfma_f32_16x16x32_bf16 %0, %1, %2, %0" : "+v"(acc) : "v"(a), "v"(b));
      }
    }
    asm volatile("s_nop 7\n\ts_nop 7\n\ts_nop 7");
    #pragma unroll
    for (int r = 0; r < 4; r++) gl[ks][g][rh*16 + qr*4 + r][col] = acc[r];
    __syncthreads();
    if (tid < 512){
      float gs0 = gl[0][0][cn][cu] + gl[1][0][cn][cu];
      float gs1 = gl[0][1][cn][cu] + gl[1][1][cn][cu];
      float gs2 = gl[0][2][cn][cu] + gl[1][2][cn][cu];
      float gs3 = gl[0][3][cn][cu] + gl[1][3][cn][cu];
      int cj = u0 + cu;
      float gi = gs0 + b2f(pre[cn*2048 + cj]);
      float gf = gs1 + b2f(pre[cn*2048 + 512 + cj]);
      float gg = gs2 + b2f(pre[cn*2048 + 1024 + cj]);
      float go = gs3 + b2f(pre[cn*2048 + 1536 + cj]);
      float ii = sigm(gi), ff = sigm(gf), g2 = tanhf(gg), oo = sigm(go);
      creg = ff*creg + ii*g2;
      float h = oo*tanhf(creg);
      float hn = __shfl_down(h, 1);
      if (!(tid & 1)){
        unsigned pk = (unsigned)f2b(h) | ((unsigned)f2b(hn) << 16);
        unsigned* addr = (unsigned*)&out[cn*1024 + u0 + cu];
        __hip_atomic_store(addr, pk, __ATOMIC_RELAXED, __HIP_MEMORY_SCOPE_AGENT);
      }
    }
    asm volatile("s_waitcnt vmcnt(0)" ::: "memory");
    __syncthreads();
    if (tid == 0){
      __hip_atomic_fetch_add(barOwn, 1u, __ATOMIC_RELAXED, __HIP_MEMORY_SCOPE_AGENT);
      if (js != nsteps - 1){
        unsigned target = base + (unsigned)(js + 1)*32u;
        int spins = 0;
        while (__hip_atomic_load(barOwn, __ATOMIC_RELAXED, __HIP_MEMORY_SCOPE_AGENT) < target){
          __builtin_amdgcn_s_sleep(1);
          if (++spins > 20000000) break;
        }
        if (joint){
          spins = 0;
          while (__hip_atomic_load(barOth, __ATOMIC_RELAXED, __HIP_MEMORY_SCOPE_AGENT) < target){
            __builtin_amdgcn_s_sleep(1);
            if (++spins > 20000000) break;
          }
        }
      }
    }
    __syncthreads();
  }
  if (tid < 512) c[cn*512 + u0 + cu] = creg;
}

extern "C" void kernel_launch(void* const* d_in, const int* in_sizes, int n_in,
                              void* d_out, int out_size, void* d_ws, size_t ws_size,
                              hipStream_t stream)
{
  const float* inp    = (const float*)d_in[0];
  const float* noise  = (const float*)d_in[1];
  const float* e0f_Wih=(const float*)d_in[2];
  const float* e0f_Whh=(const float*)d_in[3];
  const float* e0f_b  =(const float*)d_in[4];
  const float* e0b_Wih=(const float*)d_in[5];
  const float* e0b_Whh=(const float*)d_in[6];
  const float* e0b_b  =(const float*)d_in[7];
  const float* e1f_Wih=(const float*)d_in[8];
  const float* e1f_Whh=(const float*)d_in[9];
  const float* e1f_b  =(const float*)d_in[10];
  const float* e1b_Wih=(const float*)d_in[11];
  const float* e1b_Whh=(const float*)d_in[12];
  const float* e1b_b  =(const float*)d_in[13];
  const float* df_Wih =(const float*)d_in[14];
  const float* df_Whh =(const float*)d_in[15];
  const float* df_b   =(const float*)d_in[16];
  const float* db_Wih =(const float*)d_in[17];
  const float* db_Whh =(const float*)d_in[18];
  const float* db_b   =(const float*)d_in[19];
  const float* mu_W   =(const float*)d_in[20];
  const float* mu_b   =(const float*)d_in[21];
  const float* sig_W  =(const float*)d_in[22];
  const float* sig_b  =(const float*)d_in[23];
  const float* h0     =(const float*)d_in[24];
  const float* c0     =(const float*)d_in[25];
  const float* ctx_W  =(const float*)d_in[26];
  const float* ctx_b  =(const float*)d_in[27];
  const float* feat_W =(const float*)d_in[28];
  const float* feat_b =(const float*)d_in[29];
  const float* score_W=(const float*)d_in[30];
  const float* score_b=(const float*)d_in[31];

  float* dout = (float*)d_out;
  const long Y_OFF  = 0;
  const long MU_OFF = 8217600;
  const long LV_OFF = 13132800;
  const long MK_OFF = 18048000;

  // ---------------- workspace layout (~178 MB with aliasing) ----------------
  char* ws = (char*)d_ws;
  size_t off = 0;
  auto alloc = [&](size_t bytes)->char*{
    char* p = ws + off; off += (bytes + 255) & ~(size_t)255; return p;
  };
  char* regionA = alloc(25600L*1024*2);   // x1 (enc) -> dec (decoder/head)
  char* regionB = alloc(25600L*1024*2);   // inpb (18MB) -> x2 -> feat chunks
  ushort_t* preFc = (ushort_t*)alloc(3200L*2048*2);
  ushort_t* preBc = (ushort_t*)alloc(3200L*2048*2);
  ushort_t* zb    = (ushort_t*)alloc(25600L*192*2);
  ushort_t* w_e0f = (ushort_t*)alloc(2048L*352*2);
  ushort_t* w_e0b = (ushort_t*)alloc(2048L*352*2);
  ushort_t* w_e1f = (ushort_t*)alloc(2048L*1024*2);
  ushort_t* w_e1b = (ushort_t*)alloc(2048L*1024*2);
  ushort_t* w_h0f = (ushort_t*)alloc(2048L*512*2);
  ushort_t* w_h0b = (ushort_t*)alloc(2048L*512*2);
  ushort_t* w_h1f = (ushort_t*)alloc(2048L*512*2);
  ushort_t* w_h1b = (ushort_t*)alloc(2048L*512*2);
  ushort_t* w_mu  = (ushort_t*)alloc(256L*1024*2);
  ushort_t* w_sig = (ushort_t*)alloc(256L*1024*2);
  ushort_t* w_dzf = (ushort_t*)alloc(2048L*192*2);
  ushort_t* w_dzb = (ushort_t*)alloc(2048L*192*2);
  ushort_t* BfT   = (ushort_t*)alloc(2048L*1024*2);
  ushort_t* BbT   = (ushort_t*)alloc(2048L*1024*2);
  ushort_t* w_feat= (ushort_t*)alloc(2048L*1024*2);
  ushort_t* w_scr = (ushort_t*)alloc(384L*2048*2);
  float* bdF  = (float*)alloc(2048*4);
  float* bdB  = (float*)alloc(2048*4);
  float* cEF  = (float*)alloc(32L*512*4);
  float* cEB  = (float*)alloc(32L*512*4);
  float* cDF  = (float*)alloc(32L*512*4);
  float* cDB  = (float*)alloc(32L*512*4);
  ushort_t* zerob = (ushort_t*)alloc(32L*1024*2);
  ushort_t* pinit = (ushort_t*)alloc(32L*1024*2);
  unsigned* bar   = (unsigned*)alloc(256);

  ushort_t* x1    = (ushort_t*)regionA;
  ushort_t* dec   = (ushort_t*)regionA;
  ushort_t* inpb  = (ushort_t*)regionB;
  ushort_t* x2    = (ushort_t*)regionB;
  ushort_t* featc = (ushort_t*)regionB;

  if (ws_size < off){
    hipMemsetAsync(d_out, 0, (size_t)out_size*4, stream);
    return;
  }

  auto CVT=[&](const float* s, ushort_t* d, int Rs, int Cs, int c0_, int Cc, int Cd, int Rd){
    long tot = (long)Rd*Cd;
    int blocks = (int)((tot + 255)/256);
    cvt_pad<<<blocks, 256, 0, stream>>>(s, d, Rs, Cs, c0_, Cc, Cd, tot);
  };
  auto GEMM=[&](const ushort_t* A, int lda, const ushort_t* B, int ldb, const float* bias,
                int K, int Nreal, int mode, int ldc, float* oF, ushort_t* oB, int nt, int mt){
    gemm_bt<<<dim3(nt,mt), 256, 0, stream>>>(A, lda, B, ldb, bias, K, Nreal, mode, ldc, oF, oB);
  };

  // ---------------- weight/input conversions ----------------
  CVT(inp,     inpb,  25600, 321, 0, 321, 352, 25600);
  CVT(e0f_Wih, w_e0f, 2048, 321, 0, 321, 352, 2048);
  CVT(e0b_Wih, w_e0b, 2048, 321, 0, 321, 352, 2048);
  CVT(e1f_Wih, w_e1f, 2048, 1024, 0, 1024, 1024, 2048);
  CVT(e1b_Wih, w_e1b, 2048, 1024, 0, 1024, 1024, 2048);
  CVT(e0f_Whh, w_h0f, 2048, 512, 0, 512, 512, 2048);
  CVT(e0b_Whh, w_h0b, 2048, 512, 0, 512, 512, 2048);
  CVT(e1f_Whh, w_h1f, 2048, 512, 0, 512, 512, 2048);
  CVT(e1b_Whh, w_h1b, 2048, 512, 0, 512, 512, 2048);
  CVT(mu_W,    w_mu,  192, 1024, 0, 1024, 1024, 256);
  CVT(sig_W,   w_sig, 192, 1024, 0, 1024, 1024, 256);
  CVT(df_Wih,  w_dzf, 2048, 256, 0, 192, 192, 2048);
  CVT(db_Wih,  w_dzb, 2048, 256, 0, 192, 192, 2048);
  CVT(feat_W,  w_feat,2048, 1024, 0, 1024, 1024, 2048);
  CVT(score_W, w_scr, 321, 2048, 0, 2048, 2048, 384);
  fold_w<<<dim3(4,2048), 256, 0, stream>>>(df_Wih, df_Whh, ctx_W, BfT, 0);
  fold_w<<<dim3(4,2048), 256, 0, stream>>>(db_Wih, db_Whh, ctx_W, BbT, 512);
  fold_b<<<8, 256, 0, stream>>>(df_b, df_Wih, ctx_b, bdF);
  fold_b<<<8, 256, 0, stream>>>(db_b, db_Wih, ctx_b, bdB);
  hipMemsetAsync(zerob, 0, 32L*1024*2, stream);
  hipMemsetAsync(cEF, 0, 32L*512*4, stream);
  hipMemsetAsync(cEB, 0, 32L*512*4, stream);
  hipMemsetAsync(bar, 0, 256, stream);
  dec_init<<<128, 256, 0, stream>>>(h0, c0, pinit, cDF, cDB);

  const int C = 100;
  const int RPC = C*32;
  unsigned barCum = 0;
  unsigned* barF = bar;
  unsigned* barB = bar + 16;   // 64B apart

  // ---------------- encoder layer 0 ----------------
  for (int c = 0; c < 8; c++){
    int f0 = c*C;
    int b0 = 800 - (c+1)*C;
    GEMM(inpb + (long)f0*32*352, 352, w_e0f, 352, e0f_b, 352, 2048, 1, 2048, nullptr, preFc, 16, 25);
    GEMM(inpb + (long)b0*32*352, 352, w_e0b, 352, e0b_b, 352, 2048, 1, 2048, nullptr, preBc, 16, 25);
    lstm_chunk<512><<<64, 1024, 0, stream>>>(C, barCum,
      f0 ? x1 + (long)(f0-1)*32768 : zerob,
      f0 ? x1 + (long)(800-f0)*32768 + 512 : zerob,
      x1 + (long)f0*32768, x1 + (long)(799-f0)*32768 + 512,
      32768L, -32768L, 0L, 0L,
      preFc, preBc + (long)(C-1)*65536, 65536L, -65536L,
      w_h0f, w_h0b, cEF, cEB, barF, barB, 0);
    barCum += (unsigned)C*32u;
  }

  // ---------------- encoder layer 1 ----------------
  hipMemsetAsync(cEF, 0, 32L*512*4, stream);
  hipMemsetAsync(cEB, 0, 32L*512*4, stream);
  for (int c = 0; c < 8; c++){
    int f0 = c*C;
    int b0 = 800 - (c+1)*C;
    GEMM(x1 + (long)f0*32768, 1024, w_e1f, 1024, e1f_b, 1024, 2048, 1, 2048, nullptr, preFc, 16, 25);
    GEMM(x1 + (long)b0*32768, 1024, w_e1b, 1024, e1b_b, 1024, 2048, 1, 2048, nullptr, preBc, 16, 25);
    lstm_chunk<512><<<64, 1024, 0, stream>>>(C, barCum,
      f0 ? x2 + (long)(f0-1)*32768 : zerob,
      f0 ? x2 + (long)(800-f0)*32768 + 512 : zerob,
      x2 + (long)f0*32768, x2 + (long)(799-f0)*32768 + 512,
      32768L, -32768L, 0L, 0L,
      preFc, preBc + (long)(C-1)*65536, 65536L, -65536L,
      w_h1f, w_h1b, cEF, cEB, barF, barB, 0);
    barCum += (unsigned)C*32u;
  }

  // ---------------- latent heads + z ----------------
  GEMM(x2, 1024, w_mu,  1024, mu_b,  1024, 192, 3, 0, dout + MU_OFF, nullptr, 2, 200);
  GEMM(x2, 1024, w_sig, 1024, sig_b, 1024, 192, 3, 0, dout + LV_OFF, nullptr, 2, 200);
  z_make<<<(int)((4915200 + 255)/256), 256, 0, stream>>>(dout + MU_OFF, dout + LV_OFF, noise, zb);

  // ---------------- decoder ----------------
  for (int c = 0; c < 8; c++){
    int f0 = c*C;
    GEMM(zb + (long)f0*32*192, 192, w_dzf, 192, bdF, 192, 2048, 1, 2048, nullptr, preFc, 16, 25);
    GEMM(zb + (long)f0*32*192, 192, w_dzb, 192, bdB, 192, 2048, 1, 2048, nullptr, preBc, 16, 25);
    lstm_chunk<1024><<<64, 1024, 0, stream>>>(C, barCum,
      f0 ? dec + (long)(f0-1)*32768 : pinit,
      f0 ? dec + (long)(f0-1)*32768 : pinit,
      dec + (long)f0*32768, dec + (long)f0*32768 + 512,
      32768L, 32768L, 0L, -512L,
      preFc, preBc, 65536L, 65536L,
      BfT, BbT, cDF, cDB, barF, barB, 1);
    barCum += (unsigned)C*32u;
  }

  // ---------------- output head ----------------
  for (int c = 0; c < 8; c++){
    long r0 = (long)c*RPC;
    GEMM(dec + r0*1024, 1024, w_feat, 1024, feat_b, 1024, 2048, 2, 2048, nullptr, featc, 16, 25);
    GEMM(featc, 2048, w_scr, 2048, score_b, 2048, 321, 0, 321, dout + Y_OFF + r0*321, nullptr, 3, 25);
  }
  fill1<<<100, 256, 0, stream>>>(dout + MK_OFF, 25600);
}